// Round 6
// baseline (327.942 us; speedup 1.0000x reference)
//
#include <hip/hip_runtime.h>
#include <math.h>

#define BB 4
#define CC 32
#define HWSZ (512*512)
#define NMAX 128              // max instances supported (actual N=100 at runtime)
#define NP 132                // padded LDS stride (>= NMAX) for [c][n] float arrays
#define NP64 133              // padded LDS stride (>= NMAX) for u64 pair-sums
#define SS (NMAX * CC)        // 4096: per-batch stride for sums/means

#define PPB 2048              // pixels per block
#define CHUNKS (HWSZ / PPB)   // 128 chunks per batch
#define NBLK (BB * CHUNKS)    // 512 blocks -> 2 blocks/CU, co-resident by bounds

#define DSLICE 8              // dist-term slice blocks per batch
#define PAD 32                // ints per done-counter slot (128 B -> no false sharing)

#define DELTA_VAR_C 0.75f
#define DELTA_DIST_C 2.0f
#define GAMMA_C 0.001f
#define FXS 1048576.0f        // fixed-point scale 2^20
#define FXI (1.0f / 1048576.0f)
#define BIAS 16777216         // 2^24: per-add bias keeping u64 halves non-negative

#define LD4(p) (*(const float4*)(p))

// phase-A / phase-C LDS overlay (union): max 17.5 KB -> 2 blocks/CU trivially fits
struct ShA { unsigned long long s_sum[(CC / 2) * NP64]; unsigned int s_cnt[NMAX]; };
struct ShC { float m_t[CC * NP]; float s_invc[NMAX]; float red[4]; };
union ShU { ShA a; ShC c; };

// block reduce over 256 threads (4 waves of 64); result valid on tid==0
__device__ __forceinline__ float block_reduce_256(float v, float* red, int tid) {
    #pragma unroll
    for (int o = 32; o > 0; o >>= 1) v += __shfl_down(v, o, 64);
    if ((tid & 63) == 0) red[tid >> 6] = v;
    __syncthreads();
    if (tid == 0) v = red[0] + red[1] + red[2] + red[3];
    return v;
}

// ---- Single fused kernel. Deadlock-free without cooperative launch: every block
// produces BEFORE it waits, and __launch_bounds__(256,2) with 512 blocks guarantees
// full co-residency (2 blocks/CU). Barrier poll is a read-only agent-scope atomic
// load with s_sleep backoff (R3's atomicAdd-RMW poll flooded the coherence point).
__global__ __launch_bounds__(256, 2) void k_all(
    const float* __restrict__ in, const int* __restrict__ lbl,
    const int* __restrict__ n_ptr, int* __restrict__ sums_i,
    unsigned int* __restrict__ counts_u, int* __restrict__ done,
    int* __restrict__ out_acc, float* __restrict__ out)
{
    const int N = *n_ptr;
    __shared__ ShU sh;
    const int tid = threadIdx.x;
    const int b = blockIdx.x / CHUNKS;
    const int chunk = blockIdx.x % CHUNKS;
    const int p0 = chunk * PPB;

    // ---------------- Phase A: per-(batch,instance) sums + counts ----------------
    for (int i = tid; i < (CC / 2) * NP64; i += 256) sh.a.s_sum[i] = 0ull;
    for (int i = tid; i < NMAX; i += 256) sh.a.s_cnt[i] = 0u;
    __syncthreads();

    const int* lb = lbl + (size_t)b * HWSZ + p0 + tid * 8;
    int4 l4a = *(const int4*)(lb);
    int4 l4b = *(const int4*)(lb + 4);
    int lab[8] = {l4a.x, l4a.y, l4a.z, l4a.w, l4b.x, l4b.y, l4b.z, l4b.w};

    #pragma unroll
    for (int i = 0; i < 8; i++) atomicAdd(&sh.a.s_cnt[lab[i]], 1u);

    const float* p = in + (size_t)b * CC * HWSZ + p0 + (size_t)tid * 8;

    // channel pair (c, c+1) per iteration; 4 float4 loads in flight
    float4 a0 = LD4(p);            float4 b0 = LD4(p + 4);
    float4 a1 = LD4(p + HWSZ);     float4 b1 = LD4(p + HWSZ + 4);

    for (int c = 0; c < CC; c += 2) {
        float4 ca0 = a0, cb0 = b0, ca1 = a1, cb1 = b1;
        if (c + 2 < CC) {
            const float* q = p + (size_t)(c + 2) * HWSZ;
            a0 = LD4(q);          b0 = LD4(q + 4);
            a1 = LD4(q + HWSZ);   b1 = LD4(q + HWSZ + 4);
        }
        float v0[8] = {ca0.x, ca0.y, ca0.z, ca0.w, cb0.x, cb0.y, cb0.z, cb0.w};
        float v1[8] = {ca1.x, ca1.y, ca1.z, ca1.w, cb1.x, cb1.y, cb1.z, cb1.w};
        unsigned long long* row = &sh.a.s_sum[(c >> 1) * NP64];
        #pragma unroll
        for (int i = 0; i < 8; i++) {
            // truncating cvt (unbiased for symmetric data); bias keeps halves >= 0
            unsigned int lo = (unsigned int)((int)(v0[i] * FXS) + BIAS);
            unsigned int hi = (unsigned int)((int)(v1[i] * FXS) + BIAS);
            unsigned long long pk = (unsigned long long)lo |
                                    ((unsigned long long)hi << 32);
            atomicAdd(&row[lab[i]], pk);
        }
    }
    __syncthreads();

    // flush: unbias with per-label count, device-scope int atomics into zeroed ws
    for (int i = tid; i < N * CC; i += 256) {
        int n = i >> 5, c = i & 31;
        unsigned long long v = sh.a.s_sum[(c >> 1) * NP64 + n];
        unsigned int half = (c & 1) ? (unsigned int)(v >> 32) : (unsigned int)v;
        long long val = (long long)half - ((long long)sh.a.s_cnt[n] << 24);
        if (val != 0)
            atomicAdd(&sums_i[(size_t)b * SS + i], (int)val);
    }
    for (int i = tid; i < N; i += 256) {
        unsigned int cv = sh.a.s_cnt[i];
        if (cv) atomicAdd(&counts_u[b * NMAX + i], cv);
    }

    // ---- publish this chunk, then wait for the whole batch (produce-first) ----
    __threadfence();          // release: drain + write back before signaling
    __syncthreads();          // all lanes' fences done before tid0 signals
    if (tid == 0) {
        __hip_atomic_fetch_add(&done[b * PAD], 1,
                               __ATOMIC_RELEASE, __HIP_MEMORY_SCOPE_AGENT);
        // read-only coherent poll + sleep backoff: no ownership ping-pong
        while (__hip_atomic_load(&done[b * PAD],
                                 __ATOMIC_ACQUIRE, __HIP_MEMORY_SCOPE_AGENT) < CHUNKS)
            __builtin_amdgcn_s_sleep(32);
    }
    __syncthreads();
    __threadfence();          // acquire: invalidate so plain loads see fresh sums

    // ---------------- Phase C: means + variance hinge + dist + reg ----------------
    for (int i = tid; i < N; i += 256)
        sh.c.s_invc[i] = 1.0f / (float)counts_u[b * NMAX + i];
    __syncthreads();
    for (int i = tid; i < N * CC; i += 256) {
        int n = i >> 5, c = i & 31;
        sh.c.m_t[c * NP + n] = (float)sums_i[(size_t)b * SS + i] * FXI * sh.c.s_invc[n];
    }
    __syncthreads();

    float acc[8] = {0.f, 0.f, 0.f, 0.f, 0.f, 0.f, 0.f, 0.f};

    // second pass over this chunk (L3-resident after phase A); labels reused in regs
    a0 = LD4(p);            b0 = LD4(p + 4);
    a1 = LD4(p + HWSZ);     b1 = LD4(p + HWSZ + 4);

    for (int c = 0; c < CC; c += 2) {
        float4 ca0 = a0, cb0 = b0, ca1 = a1, cb1 = b1;
        if (c + 2 < CC) {
            const float* q = p + (size_t)(c + 2) * HWSZ;
            a0 = LD4(q);          b0 = LD4(q + 4);
            a1 = LD4(q + HWSZ);   b1 = LD4(q + HWSZ + 4);
        }
        float v0[8] = {ca0.x, ca0.y, ca0.z, ca0.w, cb0.x, cb0.y, cb0.z, cb0.w};
        #pragma unroll
        for (int i = 0; i < 8; i++) {
            float d = v0[i] - sh.c.m_t[c * NP + lab[i]];
            acc[i] += d * d;
        }
        float v1[8] = {cb1.x, cb1.y, cb1.z, cb1.w, cb1.x, cb1.y, cb1.z, cb1.w};
        // NOTE: corrected below — see v1 assignment
        float v1c[8] = {ca1.x, ca1.y, ca1.z, ca1.w, cb1.x, cb1.y, cb1.z, cb1.w};
        #pragma unroll
        for (int i = 0; i < 8; i++) {
            float d = v1c[i] - sh.c.m_t[(c + 1) * NP + lab[i]];
            acc[i] += d * d;
        }
        (void)v1;
    }

    float vsum = 0.f;
    #pragma unroll
    for (int i = 0; i < 8; i++) {
        float nm = sqrtf(acc[i]);
        float t = fmaxf(nm - DELTA_VAR_C, 0.f);
        vsum += t * t * sh.c.s_invc[lab[i]];
    }
    float total = vsum * (1.0f / ((float)N * (float)BB));

    // fold pairwise-distance + regularization terms into first DSLICE blocks/batch
    if (chunk < DSLICE) {
        float dist_sum = 0.f;
        for (int pr = chunk * 256 + tid; pr < N * N; pr += DSLICE * 256) {
            int i = pr / N, j = pr - i * N;
            if (i == j) continue;
            float d2 = 0.f;
            #pragma unroll
            for (int c = 0; c < CC; c++) {
                float d = sh.c.m_t[c * NP + i] - sh.c.m_t[c * NP + j];
                d2 += d * d;
            }
            float dm = (d2 > 0.f) ? sqrtf(d2) : 1.0f;   // match jnp.where(d2>0,d2,1)
            float h = fmaxf(2.0f * DELTA_DIST_C - dm, 0.f);
            dist_sum += h * h;
        }
        total += dist_sum * (1.0f / ((float)N * (float)(N - 1) * (float)BB));
        if (chunk == 0) {
            float reg_sum = 0.f;
            for (int n = tid; n < N; n += 256) {
                float s = 0.f;
                #pragma unroll
                for (int c = 0; c < CC; c++) { float v = sh.c.m_t[c * NP + n]; s += v * v; }
                reg_sum += sqrtf(s);
            }
            total += reg_sum * (GAMMA_C / ((float)N * (float)BB));
        }
    }

    float tot = block_reduce_256(total, sh.c.red, tid);
    if (tid == 0) {
        atomicAdd(out_acc, (int)rintf(tot * FXS));
        __threadfence();                       // out_acc add visible before fin add
        int prev = __hip_atomic_fetch_add(&done[BB * PAD], 1,
                                          __ATOMIC_ACQ_REL, __HIP_MEMORY_SCOPE_AGENT);
        if (prev == NBLK - 1) {
            // all NBLK out_acc RMWs precede their fin RMWs; RMW-read at the
            // coherence point observes the completed total
            int total_fx = atomicAdd(out_acc, 0);
            *out = (float)total_fx * FXI;
        }
    }
}

extern "C" void kernel_launch(void* const* d_in, const int* in_sizes, int n_in,
                              void* d_out, int out_size, void* d_ws, size_t ws_size,
                              hipStream_t stream) {
    (void)in_sizes; (void)n_in; (void)out_size; (void)ws_size;
    const float* in  = (const float*)d_in[0];
    const int*   lbl = (const int*)d_in[1];
    const int*   n_ptr = (const int*)d_in[2];
    float* out = (float*)d_out;

    // workspace layout
    int* sums_i = (int*)d_ws;                                          // BB*SS
    unsigned int* counts_u = (unsigned int*)(sums_i + BB * SS);        // BB*NMAX
    int* out_acc = (int*)(counts_u + BB * NMAX);                       // 1
    int* done    = out_acc + 1;                                        // (BB+1)*PAD

    hipMemsetAsync(d_ws, 0,
                   (size_t)(BB * SS + BB * NMAX + 1 + (BB + 1) * PAD) * sizeof(int),
                   stream);

    k_all<<<NBLK, 256, 0, stream>>>(in, lbl, n_ptr, sums_i, counts_u,
                                    done, out_acc, out);
}

// Round 7
// 232.434 us; speedup vs baseline: 1.4109x; 1.4109x over previous
//
#include <hip/hip_runtime.h>
#include <math.h>

#define BB 4
#define CC 32
#define HWSZ (512*512)
#define NMAX 128              // max instances supported (actual N=100 at runtime)
#define NP 132                // padded LDS stride (>= NMAX) for [c][n] float arrays
#define NP64 133              // padded LDS stride (>= NMAX) for u64 pair-sums
#define SS (NMAX * CC)        // 4096: per-batch stride for sums/means

#define PPB 2048              // pixels per block
#define CHUNKS (HWSZ / PPB)   // 128 chunks per batch
#define NBLK (BB * CHUNKS)    // 512 blocks

#define DSLICE 8              // dist-term slice blocks per batch (inside k_var)

#define DELTA_VAR_C 0.75f
#define DELTA_DIST_C 2.0f
#define GAMMA_C 0.001f
#define FXS 1048576.0f        // fixed-point scale 2^20
#define FXI (1.0f / 1048576.0f)
#define BIAS 16777216         // 2^24: per-add bias keeping u64 halves non-negative

#define LD4(p) (*(const float4*)(p))

// block reduce over 256 threads (4 waves of 64); result valid on tid==0
__device__ __forceinline__ float block_reduce_256(float v, float* red, int tid) {
    #pragma unroll
    for (int o = 32; o > 0; o >>= 1) v += __shfl_down(v, o, 64);
    if ((tid & 63) == 0) red[tid >> 6] = v;
    __syncthreads();
    if (tid == 0) v = red[0] + red[1] + red[2] + red[3];
    return v;
}

// ---- Kernel 1: per-(batch,instance) sums + counts; packed u64 LDS atomics.
// 4 channels per iteration, next-4 prefetched: 8 float4 (128 B/thread) in flight.
__global__ __launch_bounds__(256) void k_seg_sum(
    const float* __restrict__ in, const int* __restrict__ lbl,
    const int* __restrict__ n_ptr, int* __restrict__ sums_i,
    unsigned int* __restrict__ counts_u)
{
    const int N = *n_ptr;
    __shared__ unsigned long long s_sum[(CC / 2) * NP64];  // [c/2][n], lo=c, hi=c+1
    __shared__ unsigned int s_cnt[NMAX];
    const int tid = threadIdx.x;

    for (int i = tid; i < (CC / 2) * NP64; i += 256) s_sum[i] = 0ull;
    for (int i = tid; i < NMAX; i += 256) s_cnt[i] = 0u;
    __syncthreads();

    const int b = blockIdx.x / CHUNKS;
    const int p0 = (blockIdx.x % CHUNKS) * PPB;

    const int* lb = lbl + (size_t)b * HWSZ + p0 + tid * 8;
    int4 l4a = *(const int4*)(lb);
    int4 l4b = *(const int4*)(lb + 4);
    int lab[8] = {l4a.x, l4a.y, l4a.z, l4a.w, l4b.x, l4b.y, l4b.z, l4b.w};

    #pragma unroll
    for (int i = 0; i < 8; i++) atomicAdd(&s_cnt[lab[i]], 1u);

    const float* p = in + (size_t)b * CC * HWSZ + p0 + (size_t)tid * 8;

    // double-buffered 4-channel groups; fully unrolled -> static indexing
    float4 bufA[2][4], bufB[2][4];     // [phase][k]: px0-3 / px4-7 of channel c+k
    #pragma unroll
    for (int k = 0; k < 4; k++) {
        const float* q = p + (size_t)k * HWSZ;
        bufA[0][k] = LD4(q);  bufB[0][k] = LD4(q + 4);
    }
    #pragma unroll
    for (int k = 0; k < 4; k++) {
        const float* q = p + (size_t)(4 + k) * HWSZ;
        bufA[1][k] = LD4(q);  bufB[1][k] = LD4(q + 4);
    }

    #pragma unroll
    for (int g = 0; g < CC / 4; g++) {          // 8 groups of 4 channels
        const int ph = g & 1;
        const int c = g * 4;
        float v[4][8];
        #pragma unroll
        for (int k = 0; k < 4; k++) {
            v[k][0] = bufA[ph][k].x; v[k][1] = bufA[ph][k].y;
            v[k][2] = bufA[ph][k].z; v[k][3] = bufA[ph][k].w;
            v[k][4] = bufB[ph][k].x; v[k][5] = bufB[ph][k].y;
            v[k][6] = bufB[ph][k].z; v[k][7] = bufB[ph][k].w;
        }
        if (g + 2 < CC / 4) {                   // prefetch channels c+8..c+11
            #pragma unroll
            for (int k = 0; k < 4; k++) {
                const float* q = p + (size_t)(c + 8 + k) * HWSZ;
                bufA[ph][k] = LD4(q);  bufB[ph][k] = LD4(q + 4);
            }
        }
        unsigned long long* rowA = &s_sum[(c >> 1) * NP64];        // c, c+1
        unsigned long long* rowB = &s_sum[((c >> 1) + 1) * NP64];  // c+2, c+3
        #pragma unroll
        for (int i = 0; i < 8; i++) {
            // truncating cvt (unbiased for symmetric data); bias keeps halves >= 0
            unsigned int lo0 = (unsigned int)((int)(v[0][i] * FXS) + BIAS);
            unsigned int hi0 = (unsigned int)((int)(v[1][i] * FXS) + BIAS);
            atomicAdd(&rowA[lab[i]], (unsigned long long)lo0 |
                                     ((unsigned long long)hi0 << 32));
            unsigned int lo1 = (unsigned int)((int)(v[2][i] * FXS) + BIAS);
            unsigned int hi1 = (unsigned int)((int)(v[3][i] * FXS) + BIAS);
            atomicAdd(&rowB[lab[i]], (unsigned long long)lo1 |
                                     ((unsigned long long)hi1 << 32));
        }
    }
    __syncthreads();

    // flush: unbias with per-label count, global int atomics (L2-pipelined)
    for (int i = tid; i < N * CC; i += 256) {
        int n = i / CC, c = i % CC;
        unsigned long long v = s_sum[(c >> 1) * NP64 + n];
        unsigned int half = (c & 1) ? (unsigned int)(v >> 32) : (unsigned int)v;
        long long val = (long long)half - ((long long)s_cnt[n] << 24);
        if (val != 0)
            atomicAdd(&sums_i[(size_t)b * SS + i], (int)val);
    }
    for (int i = tid; i < N; i += 256) {
        unsigned int cv = s_cnt[i];
        if (cv) atomicAdd(&counts_u[b * NMAX + i], cv);
    }
}

// ---- Kernel 2: means + variance hinge + dist + reg, fused; last block writes out
__global__ __launch_bounds__(256) void k_var(
    const float* __restrict__ in, const int* __restrict__ lbl,
    const int* __restrict__ n_ptr, const int* __restrict__ sums_i,
    const unsigned int* __restrict__ counts_u, int* __restrict__ out_acc,
    int* __restrict__ fin, float* __restrict__ out)
{
    const int N = *n_ptr;
    __shared__ float m_t[CC * NP];   // [c][n] transposed means
    __shared__ float s_invc[NMAX];
    __shared__ float red[4];
    const int tid = threadIdx.x;

    const int b = blockIdx.x / CHUNKS;
    const int chunk = blockIdx.x % CHUNKS;
    const int p0 = chunk * PPB;

    for (int i = tid; i < N; i += 256)
        s_invc[i] = 1.0f / (float)counts_u[b * NMAX + i];
    __syncthreads();
    for (int i = tid; i < N * CC; i += 256) {
        int n = i / CC, c = i % CC;
        m_t[c * NP + n] = (float)sums_i[(size_t)b * SS + i] * FXI * s_invc[n];
    }
    __syncthreads();

    const int* lb = lbl + (size_t)b * HWSZ + p0 + tid * 8;
    int4 l4a = *(const int4*)(lb);
    int4 l4b = *(const int4*)(lb + 4);
    int lab[8] = {l4a.x, l4a.y, l4a.z, l4a.w, l4b.x, l4b.y, l4b.z, l4b.w};
    float acc[8] = {0.f, 0.f, 0.f, 0.f, 0.f, 0.f, 0.f, 0.f};

    const float* p = in + (size_t)b * CC * HWSZ + p0 + (size_t)tid * 8;

    float4 bufA[2][4], bufB[2][4];
    #pragma unroll
    for (int k = 0; k < 4; k++) {
        const float* q = p + (size_t)k * HWSZ;
        bufA[0][k] = LD4(q);  bufB[0][k] = LD4(q + 4);
    }
    #pragma unroll
    for (int k = 0; k < 4; k++) {
        const float* q = p + (size_t)(4 + k) * HWSZ;
        bufA[1][k] = LD4(q);  bufB[1][k] = LD4(q + 4);
    }

    #pragma unroll
    for (int g = 0; g < CC / 4; g++) {
        const int ph = g & 1;
        const int c = g * 4;
        float v[4][8];
        #pragma unroll
        for (int k = 0; k < 4; k++) {
            v[k][0] = bufA[ph][k].x; v[k][1] = bufA[ph][k].y;
            v[k][2] = bufA[ph][k].z; v[k][3] = bufA[ph][k].w;
            v[k][4] = bufB[ph][k].x; v[k][5] = bufB[ph][k].y;
            v[k][6] = bufB[ph][k].z; v[k][7] = bufB[ph][k].w;
        }
        if (g + 2 < CC / 4) {
            #pragma unroll
            for (int k = 0; k < 4; k++) {
                const float* q = p + (size_t)(c + 8 + k) * HWSZ;
                bufA[ph][k] = LD4(q);  bufB[ph][k] = LD4(q + 4);
            }
        }
        #pragma unroll
        for (int k = 0; k < 4; k++) {
            #pragma unroll
            for (int i = 0; i < 8; i++) {
                float d = v[k][i] - m_t[(c + k) * NP + lab[i]];
                acc[i] += d * d;
            }
        }
    }

    float vsum = 0.f;
    #pragma unroll
    for (int i = 0; i < 8; i++) {
        float nm = sqrtf(acc[i]);
        float t = fmaxf(nm - DELTA_VAR_C, 0.f);
        vsum += t * t * s_invc[lab[i]];
    }
    float total = vsum * (1.0f / ((float)N * (float)BB));

    // fold pairwise-distance + regularization terms into first DSLICE blocks/batch
    if (chunk < DSLICE) {
        float dist_sum = 0.f;
        for (int pr = chunk * 256 + tid; pr < N * N; pr += DSLICE * 256) {
            int i = pr / N, j = pr - i * N;
            if (i == j) continue;
            float d2 = 0.f;
            #pragma unroll
            for (int c = 0; c < CC; c++) {
                float d = m_t[c * NP + i] - m_t[c * NP + j];
                d2 += d * d;
            }
            float dm = (d2 > 0.f) ? sqrtf(d2) : 1.0f;   // match jnp.where(d2>0,d2,1)
            float h = fmaxf(2.0f * DELTA_DIST_C - dm, 0.f);
            dist_sum += h * h;
        }
        total += dist_sum * (1.0f / ((float)N * (float)(N - 1) * (float)BB));
        if (chunk == 0) {
            float reg_sum = 0.f;
            for (int n = tid; n < N; n += 256) {
                float s = 0.f;
                #pragma unroll
                for (int c = 0; c < CC; c++) { float v = m_t[c * NP + n]; s += v * v; }
                reg_sum += sqrtf(s);
            }
            total += reg_sum * (GAMMA_C / ((float)N * (float)BB));
        }
    }

    float tot = block_reduce_256(total, red, tid);
    if (tid == 0) {
        atomicAdd(out_acc, (int)rintf(tot * FXS));
        __threadfence();                       // out_acc add visible before fin add
        int prev = atomicAdd(fin, 1);
        if (prev == NBLK - 1) {
            // all NBLK out_acc RMWs precede their fin RMWs; RMW-read at the
            // coherence point observes the completed total
            int total_fx = atomicAdd(out_acc, 0);
            *out = (float)total_fx * FXI;
        }
    }
}

extern "C" void kernel_launch(void* const* d_in, const int* in_sizes, int n_in,
                              void* d_out, int out_size, void* d_ws, size_t ws_size,
                              hipStream_t stream) {
    (void)in_sizes; (void)n_in; (void)out_size; (void)ws_size;
    const float* in  = (const float*)d_in[0];
    const int*   lbl = (const int*)d_in[1];
    const int*   n_ptr = (const int*)d_in[2];
    float* out = (float*)d_out;

    int* sums_i = (int*)d_ws;                                          // BB*SS
    unsigned int* counts_u = (unsigned int*)(sums_i + BB * SS);        // BB*NMAX
    int* out_acc = (int*)(counts_u + BB * NMAX);                       // 1
    int* fin     = out_acc + 1;                                        // 1

    hipMemsetAsync(d_ws, 0, (size_t)(BB * SS + BB * NMAX + 2) * sizeof(int), stream);

    k_seg_sum<<<NBLK, 256, 0, stream>>>(in, lbl, n_ptr, sums_i, counts_u);
    k_var<<<NBLK, 256, 0, stream>>>(in, lbl, n_ptr, sums_i, counts_u,
                                    out_acc, fin, out);
}